// Round 11
// baseline (3376.114 us; speedup 1.0000x reference)
//
#include <hip/hip_runtime.h>

#define SEQ  2048
#define NB   8
#define HD   256
#define G3   768
#define NV   100

typedef float f32x4 __attribute__((ext_vector_type(4)));
typedef int   i32x4 __attribute__((ext_vector_type(4)));

#define INV26 1.490116119384765625e-8f   // 2^-26

__device__ __forceinline__ float sigm(float x) {
  x = fminf(fmaxf(x, -30.f), 30.f);
  return 1.f / (1.f + __expf(-x));
}
__device__ __forceinline__ float tanh_fast(float x) {
  x = fminf(fmaxf(x, -15.f), 15.f);
  float e = __expf(2.f * x);
  return (e - 1.f) / (e + 1.f);
}

// ---------------- K1: xg lookup table: table[v][g] = emb[v]·w_ih[g] + b_ih[g]
__global__ __launch_bounds__(256) void build_table(
    const float* __restrict__ emb, const float* __restrict__ w_ih,
    const float* __restrict__ b_ih, float* __restrict__ table) {
  __shared__ float eL[256];
  __shared__ float wL[256][37];
  int v = blockIdx.x, tid = threadIdx.x;
  eL[tid] = emb[v * HD + tid];
  for (int gt = 0; gt < 3; ++gt) {
    float acc = b_ih[gt * 256 + tid];
    for (int e0 = 0; e0 < HD; e0 += 32) {
      __syncthreads();
      #pragma unroll
      for (int i = 0; i < 32; ++i) {
        int idx = tid + i * 256;
        int r = idx >> 5, c = idx & 31;
        wL[r][c] = w_ih[(size_t)(gt * 256 + r) * HD + e0 + c];
      }
      __syncthreads();
      #pragma unroll
      for (int c = 0; c < 32; ++c) acc += eL[e0 + c] * wL[tid][c];
    }
    table[(size_t)v * G3 + gt * 256 + tid] = acc;
  }
}

// ---------------- K2: batch-parallel GRU scan, one WG per batch (grid=8),
// weights fully VGPR-resident (48 regs/lane, verified round 10).
// Round-10 bottleneck was LDS pipe: 64 full-width A-fragment ds_read_b128
// (~770 cyc/step, mostly zero rows) + 48 ds_bpermute shuffles (~500 cyc).
// Fixes: (a) A-reads exec-masked to lanes ncol in {0,8} (the only nonzero
// A rows: row0=hi8(q_h), row8=lou-128) -> 8x less LDS read traffic;
// (b) shfl_xor removed: quad0 writes hgA[n]=256*D0*INV26+Cn, quad2 writes
// hgB[n]=D8*INV26, gate threads sum. Same verified fixed-point math:
// q_w = round(w*2^11); hg = (256*D0 + D8 + 128*sum_k q_w)*2^-26 + b_hh.
// C/D: col=lane&15, row=(lane>>4)*4+reg -> row0 = (quad0,reg0), row8 = (quad2,reg0).
__global__ void __launch_bounds__(1024) gru_scan(
    const int* __restrict__ x, const float* __restrict__ w_hh,
    const float* __restrict__ b_hh, const float* __restrict__ table,
    float* __restrict__ all_h, float* __restrict__ h_last) {
  __shared__ __align__(16) signed char hpk[2 * 272];  // row0 hi8, row1 lou-128
  __shared__ float hgA[G3];
  __shared__ float hgB[G3];
  const int b = blockIdx.x;
  int tid = threadIdx.x;
  int lane = tid & 63, wv = tid >> 6;       // 16 waves
  int ncol = lane & 15, quad = lane >> 4;

  for (int i = tid; i < 2 * 272; i += 1024)
    hpk[i] = (i >= 272) ? (signed char)-128 : 0;

  // quantize weights into registers; wave wv owns n-tiles 3wv..3wv+2
  i32x4 bw[3][4];
  float Cn[3];
  #pragma unroll
  for (int t3 = 0; t3 < 3; ++t3) {
    int row = (wv * 3 + t3) * 16 + ncol;
    int sw = 0;
    #pragma unroll
    for (int c = 0; c < 4; ++c) {
      const float* p = w_hh + (size_t)row * HD + c * 64 + quad * 16;
      unsigned pw[4] = {0u, 0u, 0u, 0u};
      #pragma unroll
      for (int e = 0; e < 16; ++e) {
        int q = __float2int_rn(p[e] * 2048.f);       // w * 2^11
        q = max(-127, min(127, q));
        sw += q;
        pw[e >> 2] |= ((unsigned)(q & 255)) << ((e & 3) * 8);
      }
      bw[t3][c] = (i32x4){(int)pw[0], (int)pw[1], (int)pw[2], (int)pw[3]};
    }
    sw += __shfl_xor(sw, 16);
    sw += __shfl_xor(sw, 32);                        // full-K sum of q_w for row
    Cn[t3] = b_hh[row] + 128.f * (float)sw * INV26;
  }

  // gate identity: threads 0..255 handle hidden unit j = tid for batch b
  float hreg = 0.f, xr = 0.f, xz = 0.f, xn = 0.f;
  if (tid < 256) {
    int v = x[b * SEQ];
    const float* tr = table + (size_t)v * G3 + tid;
    xr = tr[0]; xz = tr[256]; xn = tr[512];
  }

  bool alive = (ncol & 7) == 0;                      // lanes holding nonzero A rows
  int a_base = (ncol >> 3) * 272 + quad * 16;

  for (int t = 0; t < SEQ; ++t) {
    __syncthreads();                                 // hpk ready
    i32x4 a[4] = {(i32x4){0,0,0,0}, (i32x4){0,0,0,0},
                  (i32x4){0,0,0,0}, (i32x4){0,0,0,0}};
    if (alive) {
      #pragma unroll
      for (int c = 0; c < 4; ++c)
        a[c] = *(const i32x4*)&hpk[a_base + c * 64];
    }
    #pragma unroll
    for (int t3 = 0; t3 < 3; ++t3) {
      i32x4 acc = {0, 0, 0, 0};
      #pragma unroll
      for (int c = 0; c < 4; ++c)
        acc = __builtin_amdgcn_mfma_i32_16x16x64_i8(a[c], bw[t3][c], acc, 0, 0, 0);
      int n = (wv * 3 + t3) * 16 + ncol;
      if (quad == 0)      hgA[n] = (float)acc[0] * (256.f * INV26) + Cn[t3];
      else if (quad == 2) hgB[n] = (float)acc[0] * INV26;
    }
    __syncthreads();                                 // hgA/hgB ready
    if (tid < 256) {
      int j = tid;
      float r = sigm(xr + hgA[j]       + hgB[j]);
      float z = sigm(xz + hgA[256 + j] + hgB[256 + j]);
      float n = tanh_fast(xn + (hgA[512 + j] + hgB[512 + j]) * r);
      float h = (1.f - z) * n + z * hreg;
      hreg = h;
      int q = min(__float2int_rn(h * 32768.f), 32767);
      int lou = q & 255;
      int hi8 = (q - lou) >> 8;
      hpk[j] = (signed char)hi8;
      hpk[272 + j] = (signed char)(lou - 128);
      all_h[((size_t)b * SEQ + t) * HD + j] = h;
      int tn = (t + 1 < SEQ) ? t + 1 : t;            // prefetch next step's xg
      int v = x[b * SEQ + tn];
      const float* tr = table + (size_t)v * G3 + j;
      xr = tr[0]; xz = tr[256]; xn = tr[512];
    }
  }
  if (tid < 256) h_last[b * HD + tid] = hreg;
}

// ---------------- generic f32 GEMM  C[M,N] = A[M,K]·W[N,K]^T + bias
template<int ACT>
__global__ __launch_bounds__(256) void gemm_bias(
    const float* __restrict__ A, int lda,
    const float* __restrict__ W, const float* __restrict__ bias,
    float* __restrict__ C, int ldc, int N, int K) {
  __shared__ float As[128][36];
  __shared__ float Ws[64][36];
  int tid = threadIdx.x;
  int m0 = blockIdx.y * 128, n0 = blockIdx.x * 64;
  int ml = tid & 31, g = tid >> 5;
  float acc[4][8];
  #pragma unroll
  for (int i = 0; i < 4; ++i)
    #pragma unroll
    for (int jj = 0; jj < 8; ++jj) acc[i][jj] = 0.f;
  for (int k0 = 0; k0 < K; k0 += 32) {
    __syncthreads();
    #pragma unroll
    for (int i = 0; i < 4; ++i) {
      int idx = tid + i * 256;
      int r = idx >> 3, c4 = (idx & 7) * 4;
      *(f32x4*)&As[r][c4] = *(const f32x4*)&A[(size_t)(m0 + r) * lda + k0 + c4];
    }
    #pragma unroll
    for (int i = 0; i < 2; ++i) {
      int idx = tid + i * 256;
      int r = idx >> 3, c4 = (idx & 7) * 4;
      f32x4 wv = {0.f, 0.f, 0.f, 0.f};
      if (n0 + r < N) wv = *(const f32x4*)&W[(size_t)(n0 + r) * K + k0 + c4];
      *(f32x4*)&Ws[r][c4] = wv;
    }
    __syncthreads();
    #pragma unroll
    for (int k4 = 0; k4 < 32; k4 += 4) {
      f32x4 av[4], wv8[8];
      #pragma unroll
      for (int i = 0; i < 4; ++i) av[i] = *(const f32x4*)&As[ml + i * 32][k4];
      #pragma unroll
      for (int jj = 0; jj < 8; ++jj) wv8[jj] = *(const f32x4*)&Ws[g * 8 + jj][k4];
      #pragma unroll
      for (int kk = 0; kk < 4; ++kk)
        #pragma unroll
        for (int i = 0; i < 4; ++i)
          #pragma unroll
          for (int jj = 0; jj < 8; ++jj)
            acc[i][jj] += av[i][kk] * wv8[jj][kk];
    }
  }
  #pragma unroll
  for (int i = 0; i < 4; ++i) {
    int m = m0 + ml + i * 32;
    #pragma unroll
    for (int jj = 0; jj < 8; ++jj) {
      int n = n0 + g * 8 + jj;
      if (n < N) {
        float val = acc[i][jj] + bias[n];
        if (ACT) val = tanh_fast(val);
        C[(size_t)m * ldc + n] = val;
      }
    }
  }
}

// ---------------- comb GEMM: A = [all_h | ctx] split-K (K=512), tanh epilogue
__global__ __launch_bounds__(256) void gemm_bias_cat(
    const float* __restrict__ A1, const float* __restrict__ A2,
    const float* __restrict__ W, const float* __restrict__ bias,
    float* __restrict__ C) {
  __shared__ float As[128][36];
  __shared__ float Ws[64][36];
  const int K = 512;
  int tid = threadIdx.x;
  int m0 = blockIdx.y * 128, n0 = blockIdx.x * 64;
  int ml = tid & 31, g = tid >> 5;
  float acc[4][8];
  #pragma unroll
  for (int i = 0; i < 4; ++i)
    #pragma unroll
    for (int jj = 0; jj < 8; ++jj) acc[i][jj] = 0.f;
  for (int k0 = 0; k0 < K; k0 += 32) {
    const float* src = (k0 < 256) ? A1 : A2;
    int kb = (k0 < 256) ? k0 : k0 - 256;
    __syncthreads();
    #pragma unroll
    for (int i = 0; i < 4; ++i) {
      int idx = tid + i * 256;
      int r = idx >> 3, c4 = (idx & 7) * 4;
      *(f32x4*)&As[r][c4] = *(const f32x4*)&src[(size_t)(m0 + r) * 256 + kb + c4];
    }
    #pragma unroll
    for (int i = 0; i < 2; ++i) {
      int idx = tid + i * 256;
      int r = idx >> 3, c4 = (idx & 7) * 4;
      *(f32x4*)&Ws[r][c4] = *(const f32x4*)&W[(size_t)(n0 + r) * K + k0 + c4];
    }
    __syncthreads();
    #pragma unroll
    for (int k4 = 0; k4 < 32; k4 += 4) {
      f32x4 av[4], wv8[8];
      #pragma unroll
      for (int i = 0; i < 4; ++i) av[i] = *(const f32x4*)&As[ml + i * 32][k4];
      #pragma unroll
      for (int jj = 0; jj < 8; ++jj) wv8[jj] = *(const f32x4*)&Ws[g * 8 + jj][k4];
      #pragma unroll
      for (int kk = 0; kk < 4; ++kk)
        #pragma unroll
        for (int i = 0; i < 4; ++i)
          #pragma unroll
          for (int jj = 0; jj < 8; ++jj)
            acc[i][jj] += av[i][kk] * wv8[jj][kk];
    }
  }
  #pragma unroll
  for (int i = 0; i < 4; ++i) {
    int m = m0 + ml + i * 32;
    #pragma unroll
    for (int jj = 0; jj < 8; ++jj) {
      int n = n0 + g * 8 + jj;
      C[(size_t)m * 256 + n] = tanh_fast(acc[i][jj] + bias[n]);
    }
  }
}

// ---------------- K4: causal flash attention, q-tile 32 / k-tile 16, all f32.
// One phase per block (blockIdx.z selects qt = jb or 63-jb) -> 512 blocks,
// 2 blocks/CU (LDS 66.5 KB each) to saturate the LDS pipe (round 10: 1
// block/CU = 4 waves left LDS latency unhidden). Qs/Ks XOR-swizzled.
__global__ __launch_bounds__(256) void attention_kernel(
    const float* __restrict__ all_h, const float* __restrict__ keys,
    float* __restrict__ ctx) {
  __shared__ float Qs[32 * 256];
  __shared__ float Ks[16 * 256];
  __shared__ float Hs[16 * 256];
  __shared__ float Sl[32][17];
  __shared__ float mL[32], lL[32], aL[32];
  int b = blockIdx.y, jb = blockIdx.x, tid = threadIdx.x;
  const float* hb = all_h + (size_t)b * SEQ * HD;
  const float* kb = keys  + (size_t)b * SEQ * HD;
  int qg = tid & 15, hi = tid >> 4;
  int r0 = qg * 2, r1 = r0 + 1;
  int sq = qg & 7;                          // Q swizzle bits for rows r0,r1
  int qt = blockIdx.z ? (63 - jb) : jb;
  int q0 = qt * 32;
  #pragma unroll
  for (int i = 0; i < 8; ++i) {             // stage Q 32x256 (swizzled)
    int idx = tid + i * 256;
    int r = idx >> 6, cg = idx & 63;
    *(f32x4*)&Qs[r * 256 + ((cg ^ ((r >> 1) & 7)) << 2)] =
        *(const f32x4*)&hb[(size_t)(q0 + r) * HD + cg * 4];
  }
  if (tid < 32) { mL[tid] = -3e38f; lL[tid] = 0.f; }
  float O0[16], O1[16];
  #pragma unroll
  for (int c = 0; c < 16; ++c) { O0[c] = 0.f; O1[c] = 0.f; }
  int nkt = 2 * (qt + 1);
  for (int kt = 0; kt < nkt; ++kt) {
    int k0 = kt * 16;
    __syncthreads();
    #pragma unroll
    for (int i = 0; i < 4; ++i) {           // stage K (swizzled) + V, 16x256 each
      int idx = tid + i * 256;
      int r = idx >> 6, cg = idx & 63;
      *(f32x4*)&Ks[r * 256 + ((cg ^ (r & 7)) << 2)] =
          *(const f32x4*)&kb[(size_t)(k0 + r) * HD + cg * 4];
      *(f32x4*)&Hs[r * 256 + cg * 4] = *(const f32x4*)&hb[(size_t)(k0 + r) * HD + cg * 4];
    }
    __syncthreads();
    int kc = hi;
    int sk = kc & 7;
    float sc0 = 0.f, sc1 = 0.f;
    #pragma unroll 8
    for (int c = 0; c < 64; ++c) {
      f32x4 kv  = *(const f32x4*)&Ks[kc * 256 + ((c ^ sk) << 2)];
      f32x4 q0v = *(const f32x4*)&Qs[r0 * 256 + ((c ^ sq) << 2)];
      f32x4 q1v = *(const f32x4*)&Qs[r1 * 256 + ((c ^ sq) << 2)];
      sc0 += q0v[0]*kv[0] + q0v[1]*kv[1] + q0v[2]*kv[2] + q0v[3]*kv[3];
      sc1 += q1v[0]*kv[0] + q1v[1]*kv[1] + q1v[2]*kv[2] + q1v[3]*kv[3];
    }
    int kabs = k0 + kc;
    Sl[r0][kc] = (kabs <= q0 + r0) ? sc0 : -3e38f;
    Sl[r1][kc] = (kabs <= q0 + r1) ? sc1 : -3e38f;
    __syncthreads();
    if (tid < 32) {                         // online softmax per q-row
      float mo = mL[tid], mn = mo;
      #pragma unroll
      for (int c = 0; c < 16; ++c) mn = fmaxf(mn, Sl[tid][c]);
      float al = __expf(mo - mn);
      float sm = 0.f;
      #pragma unroll
      for (int c = 0; c < 16; ++c) {
        float p = __expf(Sl[tid][c] - mn);
        Sl[tid][c] = p; sm += p;
      }
      lL[tid] = lL[tid] * al + sm;
      mL[tid] = mn;
      aL[tid] = al;
    }
    __syncthreads();
    float a0 = aL[r0], a1 = aL[r1];
    #pragma unroll
    for (int c = 0; c < 16; ++c) { O0[c] *= a0; O1[c] *= a1; }
    #pragma unroll
    for (int k = 0; k < 16; ++k) {
      float p0 = Sl[r0][k], p1 = Sl[r1][k];
      #pragma unroll
      for (int c4 = 0; c4 < 4; ++c4) {
        f32x4 hh = *(const f32x4*)&Hs[k * 256 + hi * 16 + c4 * 4];
        O0[c4*4+0] += p0 * hh[0]; O0[c4*4+1] += p0 * hh[1];
        O0[c4*4+2] += p0 * hh[2]; O0[c4*4+3] += p0 * hh[3];
        O1[c4*4+0] += p1 * hh[0]; O1[c4*4+1] += p1 * hh[1];
        O1[c4*4+2] += p1 * hh[2]; O1[c4*4+3] += p1 * hh[3];
      }
    }
  }
  float li0 = 1.f / lL[r0], li1 = 1.f / lL[r1];
  float* d0 = &ctx[((size_t)b * SEQ + q0 + r0) * 256 + hi * 16];
  float* d1 = &ctx[((size_t)b * SEQ + q0 + r1) * 256 + hi * 16];
  #pragma unroll
  for (int c4 = 0; c4 < 4; ++c4) {
    f32x4 v0, v1;
    #pragma unroll
    for (int c = 0; c < 4; ++c) { v0[c] = O0[c4*4+c] * li0; v1[c] = O1[c4*4+c] * li1; }
    *(f32x4*)&d0[c4*4] = v0;
    *(f32x4*)&d1[c4*4] = v1;
  }
}

extern "C" void kernel_launch(void* const* d_in, const int* in_sizes, int n_in,
                              void* d_out, int out_size, void* d_ws, size_t ws_size,
                              hipStream_t stream) {
  (void)in_sizes; (void)n_in; (void)out_size; (void)ws_size;
  const int*   x      = (const int*)  d_in[0];
  const float* emb    = (const float*)d_in[1];
  const float* w_ih   = (const float*)d_in[2];
  const float* w_hh   = (const float*)d_in[3];
  const float* b_ih   = (const float*)d_in[4];
  const float* b_hh   = (const float*)d_in[5];
  const float* attn_w = (const float*)d_in[6];
  const float* attn_b = (const float*)d_in[7];
  const float* comb_w = (const float*)d_in[8];
  const float* comb_b = (const float*)d_in[9];
  const float* fc_w   = (const float*)d_in[10];
  const float* fc_b   = (const float*)d_in[11];
  float* out = (float*)d_out;

  // workspace layout (floats): table | all_h | keys(->combined) | ctx
  float* ws    = (float*)d_ws;
  float* table = ws;                        // 100*768      =    76800
  float* all_h = table + 76800;             // 16384*256    =  4194304
  float* keys  = all_h + 4194304;           // 16384*256    =  4194304
  float* ctx   = keys  + 4194304;           // 16384*256    =  4194304
  float* hlast = out + (size_t)NB * SEQ * NV;

  build_table<<<100, 256, 0, stream>>>(emb, w_ih, b_ih, table);
  gru_scan<<<NB, 1024, 0, stream>>>(x, w_hh, b_hh, table, all_h, hlast);
  // keys = all_h @ attn_w^T + attn_b
  gemm_bias<0><<<dim3(4, 128), 256, 0, stream>>>(all_h, 256, attn_w, attn_b, keys, 256, 256, 256);
  // ctx = softmax(causal(all_h @ keys^T)) @ all_h
  attention_kernel<<<dim3(32, 8, 2), 256, 0, stream>>>(all_h, keys, ctx);
  // combined = tanh([all_h|ctx] @ comb_w^T + comb_b)  (into keys buffer)
  gemm_bias_cat<<<dim3(4, 128), 256, 0, stream>>>(all_h, ctx, comb_w, comb_b, keys);
  // out = combined @ fc_w^T + fc_b
  gemm_bias<0><<<dim3(2, 128), 256, 0, stream>>>(keys, 256, fc_w, fc_b, out, 100, 100, 256);
}

// Round 12
// 3151.810 us; speedup vs baseline: 1.0712x; 1.0712x over previous
//
#include <hip/hip_runtime.h>

#define SEQ  2048
#define NB   8
#define HD   256
#define G3   768
#define NV   100

typedef float f32x4 __attribute__((ext_vector_type(4)));
typedef int   i32x4 __attribute__((ext_vector_type(4)));

#define INV26 1.490116119384765625e-8f   // 2^-26

// LDS-only workgroup barrier: waits ds ops (lgkmcnt) but does NOT drain
// vmcnt — __syncthreads() emits s_waitcnt vmcnt(0) which forced a ~600 cyc
// HBM store-ack + prefetch-load drain into every scan step (round 11 PM).
#define LDS_BARRIER() asm volatile("s_waitcnt lgkmcnt(0)\n\ts_barrier" ::: "memory")

__device__ __forceinline__ float sigm(float x) {
  x = fminf(fmaxf(x, -30.f), 30.f);
  return 1.f / (1.f + __expf(-x));
}
__device__ __forceinline__ float tanh_fast(float x) {
  x = fminf(fmaxf(x, -15.f), 15.f);
  float e = __expf(2.f * x);
  return (e - 1.f) / (e + 1.f);
}

// ---------------- K1: xg lookup table: table[v][g] = emb[v]·w_ih[g] + b_ih[g]
__global__ __launch_bounds__(256) void build_table(
    const float* __restrict__ emb, const float* __restrict__ w_ih,
    const float* __restrict__ b_ih, float* __restrict__ table) {
  __shared__ float eL[256];
  __shared__ float wL[256][37];
  int v = blockIdx.x, tid = threadIdx.x;
  eL[tid] = emb[v * HD + tid];
  for (int gt = 0; gt < 3; ++gt) {
    float acc = b_ih[gt * 256 + tid];
    for (int e0 = 0; e0 < HD; e0 += 32) {
      __syncthreads();
      #pragma unroll
      for (int i = 0; i < 32; ++i) {
        int idx = tid + i * 256;
        int r = idx >> 5, c = idx & 31;
        wL[r][c] = w_ih[(size_t)(gt * 256 + r) * HD + e0 + c];
      }
      __syncthreads();
      #pragma unroll
      for (int c = 0; c < 32; ++c) acc += eL[e0 + c] * wL[tid][c];
    }
    table[(size_t)v * G3 + gt * 256 + tid] = acc;
  }
}

// ---------------- K2: batch-parallel GRU scan, one WG per batch (grid=8),
// weights resident (48 regs/lane incl. AGPR file). Round-11 post-mortem:
// the bottleneck was NOT the LDS pipe but __syncthreads' vmcnt(0) drain
// (~1800 cyc/step across 2 barriers waiting on the all_h store + table
// prefetch loads). Both barriers are now LDS-only (lgkmcnt drain only):
// stores retire async; prefetch loads get a full step (~2000 cyc) of
// latency cover before their vmcnt(N) wait at use.
// Verified i8 fixed-point math (rounds 8-11): q_w = round(w*2^11);
// q_h = hi8*256 + lou; A row0 = hi8, row8 = lou-128;
// hg = (256*D0 + D8 + 128*sum_k q_w)*2^-26 + b_hh.
// C/D: col=lane&15, row=(lane>>4)*4+reg -> row0 = (quad0,reg0), row8 = (quad2,reg0).
__global__ void __launch_bounds__(1024) gru_scan(
    const int* __restrict__ x, const float* __restrict__ w_hh,
    const float* __restrict__ b_hh, const float* __restrict__ table,
    float* __restrict__ all_h, float* __restrict__ h_last) {
  __shared__ __align__(16) signed char hpk[2 * 272];  // row0 hi8, row1 lou-128
  __shared__ float hgA[G3];
  __shared__ float hgB[G3];
  const int b = blockIdx.x;
  int tid = threadIdx.x;
  int lane = tid & 63, wv = tid >> 6;       // 16 waves
  int ncol = lane & 15, quad = lane >> 4;

  for (int i = tid; i < 2 * 272; i += 1024)
    hpk[i] = (i >= 272) ? (signed char)-128 : 0;

  // quantize weights into registers; wave wv owns n-tiles 3wv..3wv+2
  i32x4 bw[3][4];
  float Cn[3];
  #pragma unroll
  for (int t3 = 0; t3 < 3; ++t3) {
    int row = (wv * 3 + t3) * 16 + ncol;
    int sw = 0;
    #pragma unroll
    for (int c = 0; c < 4; ++c) {
      const float* p = w_hh + (size_t)row * HD + c * 64 + quad * 16;
      unsigned pw[4] = {0u, 0u, 0u, 0u};
      #pragma unroll
      for (int e = 0; e < 16; ++e) {
        int q = __float2int_rn(p[e] * 2048.f);       // w * 2^11
        q = max(-127, min(127, q));
        sw += q;
        pw[e >> 2] |= ((unsigned)(q & 255)) << ((e & 3) * 8);
      }
      bw[t3][c] = (i32x4){(int)pw[0], (int)pw[1], (int)pw[2], (int)pw[3]};
    }
    sw += __shfl_xor(sw, 16);
    sw += __shfl_xor(sw, 32);                        // full-K sum of q_w for row
    Cn[t3] = b_hh[row] + 128.f * (float)sw * INV26;
  }

  // gate identity: threads 0..255 handle hidden unit j = tid for batch b
  float hreg = 0.f, xr = 0.f, xz = 0.f, xn = 0.f;
  if (tid < 256) {
    int v = x[b * SEQ];
    const float* tr = table + (size_t)v * G3 + tid;
    xr = tr[0]; xz = tr[256]; xn = tr[512];
  }

  bool alive = (ncol & 7) == 0;                      // lanes holding nonzero A rows
  int a_base = (ncol >> 3) * 272 + quad * 16;

  for (int t = 0; t < SEQ; ++t) {
    LDS_BARRIER();                                   // hpk ready (LDS-only drain)
    i32x4 a[4] = {(i32x4){0,0,0,0}, (i32x4){0,0,0,0},
                  (i32x4){0,0,0,0}, (i32x4){0,0,0,0}};
    if (alive) {
      #pragma unroll
      for (int c = 0; c < 4; ++c)
        a[c] = *(const i32x4*)&hpk[a_base + c * 64];
    }
    #pragma unroll
    for (int t3 = 0; t3 < 3; ++t3) {
      i32x4 acc = {0, 0, 0, 0};
      #pragma unroll
      for (int c = 0; c < 4; ++c)
        acc = __builtin_amdgcn_mfma_i32_16x16x64_i8(a[c], bw[t3][c], acc, 0, 0, 0);
      int n = (wv * 3 + t3) * 16 + ncol;
      if (quad == 0)      hgA[n] = (float)acc[0] * (256.f * INV26) + Cn[t3];
      else if (quad == 2) hgB[n] = (float)acc[0] * INV26;
    }
    LDS_BARRIER();                                   // hgA/hgB ready
    if (tid < 256) {
      int j = tid;
      float r = sigm(xr + hgA[j]       + hgB[j]);
      float z = sigm(xz + hgA[256 + j] + hgB[256 + j]);
      float n = tanh_fast(xn + (hgA[512 + j] + hgB[512 + j]) * r);
      float h = (1.f - z) * n + z * hreg;
      hreg = h;
      int q = min(__float2int_rn(h * 32768.f), 32767);
      int lou = q & 255;
      int hi8 = (q - lou) >> 8;
      hpk[j] = (signed char)hi8;
      hpk[272 + j] = (signed char)(lou - 128);
      all_h[((size_t)b * SEQ + t) * HD + j] = h;     // async; never drained in-loop
      int tn = (t + 1 < SEQ) ? t + 1 : t;            // prefetch next step's xg
      int v = x[b * SEQ + tn];
      const float* tr = table + (size_t)v * G3 + j;
      xr = tr[0]; xz = tr[256]; xn = tr[512];
    }
  }
  if (tid < 256) h_last[b * HD + tid] = hreg;
}

// ---------------- generic f32 GEMM  C[M,N] = A[M,K]·W[N,K]^T + bias
template<int ACT>
__global__ __launch_bounds__(256) void gemm_bias(
    const float* __restrict__ A, int lda,
    const float* __restrict__ W, const float* __restrict__ bias,
    float* __restrict__ C, int ldc, int N, int K) {
  __shared__ float As[128][36];
  __shared__ float Ws[64][36];
  int tid = threadIdx.x;
  int m0 = blockIdx.y * 128, n0 = blockIdx.x * 64;
  int ml = tid & 31, g = tid >> 5;
  float acc[4][8];
  #pragma unroll
  for (int i = 0; i < 4; ++i)
    #pragma unroll
    for (int jj = 0; jj < 8; ++jj) acc[i][jj] = 0.f;
  for (int k0 = 0; k0 < K; k0 += 32) {
    __syncthreads();
    #pragma unroll
    for (int i = 0; i < 4; ++i) {
      int idx = tid + i * 256;
      int r = idx >> 3, c4 = (idx & 7) * 4;
      *(f32x4*)&As[r][c4] = *(const f32x4*)&A[(size_t)(m0 + r) * lda + k0 + c4];
    }
    #pragma unroll
    for (int i = 0; i < 2; ++i) {
      int idx = tid + i * 256;
      int r = idx >> 3, c4 = (idx & 7) * 4;
      f32x4 wv = {0.f, 0.f, 0.f, 0.f};
      if (n0 + r < N) wv = *(const f32x4*)&W[(size_t)(n0 + r) * K + k0 + c4];
      *(f32x4*)&Ws[r][c4] = wv;
    }
    __syncthreads();
    #pragma unroll
    for (int k4 = 0; k4 < 32; k4 += 4) {
      f32x4 av[4], wv8[8];
      #pragma unroll
      for (int i = 0; i < 4; ++i) av[i] = *(const f32x4*)&As[ml + i * 32][k4];
      #pragma unroll
      for (int jj = 0; jj < 8; ++jj) wv8[jj] = *(const f32x4*)&Ws[g * 8 + jj][k4];
      #pragma unroll
      for (int kk = 0; kk < 4; ++kk)
        #pragma unroll
        for (int i = 0; i < 4; ++i)
          #pragma unroll
          for (int jj = 0; jj < 8; ++jj)
            acc[i][jj] += av[i][kk] * wv8[jj][kk];
    }
  }
  #pragma unroll
  for (int i = 0; i < 4; ++i) {
    int m = m0 + ml + i * 32;
    #pragma unroll
    for (int jj = 0; jj < 8; ++jj) {
      int n = n0 + g * 8 + jj;
      if (n < N) {
        float val = acc[i][jj] + bias[n];
        if (ACT) val = tanh_fast(val);
        C[(size_t)m * ldc + n] = val;
      }
    }
  }
}

// ---------------- comb GEMM: A = [all_h | ctx] split-K (K=512), tanh epilogue
__global__ __launch_bounds__(256) void gemm_bias_cat(
    const float* __restrict__ A1, const float* __restrict__ A2,
    const float* __restrict__ W, const float* __restrict__ bias,
    float* __restrict__ C) {
  __shared__ float As[128][36];
  __shared__ float Ws[64][36];
  const int K = 512;
  int tid = threadIdx.x;
  int m0 = blockIdx.y * 128, n0 = blockIdx.x * 64;
  int ml = tid & 31, g = tid >> 5;
  float acc[4][8];
  #pragma unroll
  for (int i = 0; i < 4; ++i)
    #pragma unroll
    for (int jj = 0; jj < 8; ++jj) acc[i][jj] = 0.f;
  for (int k0 = 0; k0 < K; k0 += 32) {
    const float* src = (k0 < 256) ? A1 : A2;
    int kb = (k0 < 256) ? k0 : k0 - 256;
    __syncthreads();
    #pragma unroll
    for (int i = 0; i < 4; ++i) {
      int idx = tid + i * 256;
      int r = idx >> 3, c4 = (idx & 7) * 4;
      *(f32x4*)&As[r][c4] = *(const f32x4*)&src[(size_t)(m0 + r) * 256 + kb + c4];
    }
    #pragma unroll
    for (int i = 0; i < 2; ++i) {
      int idx = tid + i * 256;
      int r = idx >> 3, c4 = (idx & 7) * 4;
      *(f32x4*)&Ws[r][c4] = *(const f32x4*)&W[(size_t)(n0 + r) * K + k0 + c4];
    }
    __syncthreads();
    #pragma unroll
    for (int k4 = 0; k4 < 32; k4 += 4) {
      f32x4 av[4], wv8[8];
      #pragma unroll
      for (int i = 0; i < 4; ++i) av[i] = *(const f32x4*)&As[ml + i * 32][k4];
      #pragma unroll
      for (int jj = 0; jj < 8; ++jj) wv8[jj] = *(const f32x4*)&Ws[g * 8 + jj][k4];
      #pragma unroll
      for (int kk = 0; kk < 4; ++kk)
        #pragma unroll
        for (int i = 0; i < 4; ++i)
          #pragma unroll
          for (int jj = 0; jj < 8; ++jj)
            acc[i][jj] += av[i][kk] * wv8[jj][kk];
    }
  }
  #pragma unroll
  for (int i = 0; i < 4; ++i) {
    int m = m0 + ml + i * 32;
    #pragma unroll
    for (int jj = 0; jj < 8; ++jj) {
      int n = n0 + g * 8 + jj;
      C[(size_t)m * 256 + n] = tanh_fast(acc[i][jj] + bias[n]);
    }
  }
}

// ---------------- K4: causal flash attention, q-tile 32 / k-tile 16, all f32.
// Block (jb, b) handles q-tiles jb and 63-jb: the pairing balances the causal
// triangle (round 11's z-split broke this and cost ~250 us). Qs/Ks swizzled.
__global__ __launch_bounds__(256) void attention_kernel(
    const float* __restrict__ all_h, const float* __restrict__ keys,
    float* __restrict__ ctx) {
  __shared__ float Qs[32 * 256];
  __shared__ float Ks[16 * 256];
  __shared__ float Hs[16 * 256];
  __shared__ float Sl[32][17];
  __shared__ float mL[32], lL[32], aL[32];
  int b = blockIdx.y, jb = blockIdx.x, tid = threadIdx.x;
  const float* hb = all_h + (size_t)b * SEQ * HD;
  const float* kb = keys  + (size_t)b * SEQ * HD;
  int qg = tid & 15, hi = tid >> 4;
  int r0 = qg * 2, r1 = r0 + 1;
  int sq = qg & 7;                          // Q swizzle bits for rows r0,r1
  for (int phase = 0; phase < 2; ++phase) {
    int qt = phase ? (63 - jb) : jb;
    int q0 = qt * 32;
    __syncthreads();
    #pragma unroll
    for (int i = 0; i < 8; ++i) {           // stage Q 32x256 (swizzled)
      int idx = tid + i * 256;
      int r = idx >> 6, cg = idx & 63;
      *(f32x4*)&Qs[r * 256 + ((cg ^ ((r >> 1) & 7)) << 2)] =
          *(const f32x4*)&hb[(size_t)(q0 + r) * HD + cg * 4];
    }
    if (tid < 32) { mL[tid] = -3e38f; lL[tid] = 0.f; }
    float O0[16], O1[16];
    #pragma unroll
    for (int c = 0; c < 16; ++c) { O0[c] = 0.f; O1[c] = 0.f; }
    int nkt = 2 * (qt + 1);
    for (int kt = 0; kt < nkt; ++kt) {
      int k0 = kt * 16;
      __syncthreads();
      #pragma unroll
      for (int i = 0; i < 4; ++i) {         // stage K (swizzled) + V, 16x256 each
        int idx = tid + i * 256;
        int r = idx >> 6, cg = idx & 63;
        *(f32x4*)&Ks[r * 256 + ((cg ^ (r & 7)) << 2)] =
            *(const f32x4*)&kb[(size_t)(k0 + r) * HD + cg * 4];
        *(f32x4*)&Hs[r * 256 + cg * 4] = *(const f32x4*)&hb[(size_t)(k0 + r) * HD + cg * 4];
      }
      __syncthreads();
      int kc = hi;
      int sk = kc & 7;
      float sc0 = 0.f, sc1 = 0.f;
      #pragma unroll 8
      for (int c = 0; c < 64; ++c) {
        f32x4 kv  = *(const f32x4*)&Ks[kc * 256 + ((c ^ sk) << 2)];
        f32x4 q0v = *(const f32x4*)&Qs[r0 * 256 + ((c ^ sq) << 2)];
        f32x4 q1v = *(const f32x4*)&Qs[r1 * 256 + ((c ^ sq) << 2)];
        sc0 += q0v[0]*kv[0] + q0v[1]*kv[1] + q0v[2]*kv[2] + q0v[3]*kv[3];
        sc1 += q1v[0]*kv[0] + q1v[1]*kv[1] + q1v[2]*kv[2] + q1v[3]*kv[3];
      }
      int kabs = k0 + kc;
      Sl[r0][kc] = (kabs <= q0 + r0) ? sc0 : -3e38f;
      Sl[r1][kc] = (kabs <= q0 + r1) ? sc1 : -3e38f;
      __syncthreads();
      if (tid < 32) {                       // online softmax per q-row
        float mo = mL[tid], mn = mo;
        #pragma unroll
        for (int c = 0; c < 16; ++c) mn = fmaxf(mn, Sl[tid][c]);
        float al = __expf(mo - mn);
        float sm = 0.f;
        #pragma unroll
        for (int c = 0; c < 16; ++c) {
          float p = __expf(Sl[tid][c] - mn);
          Sl[tid][c] = p; sm += p;
        }
        lL[tid] = lL[tid] * al + sm;
        mL[tid] = mn;
        aL[tid] = al;
      }
      __syncthreads();
      float a0 = aL[r0], a1 = aL[r1];
      #pragma unroll
      for (int c = 0; c < 16; ++c) { O0[c] *= a0; O1[c] *= a1; }
      #pragma unroll
      for (int k = 0; k < 16; ++k) {
        float p0 = Sl[r0][k], p1 = Sl[r1][k];
        #pragma unroll
        for (int c4 = 0; c4 < 4; ++c4) {
          f32x4 hh = *(const f32x4*)&Hs[k * 256 + hi * 16 + c4 * 4];
          O0[c4*4+0] += p0 * hh[0]; O0[c4*4+1] += p0 * hh[1];
          O0[c4*4+2] += p0 * hh[2]; O0[c4*4+3] += p0 * hh[3];
          O1[c4*4+0] += p1 * hh[0]; O1[c4*4+1] += p1 * hh[1];
          O1[c4*4+2] += p1 * hh[2]; O1[c4*4+3] += p1 * hh[3];
        }
      }
    }
    float li0 = 1.f / lL[r0], li1 = 1.f / lL[r1];
    float* d0 = &ctx[((size_t)b * SEQ + q0 + r0) * 256 + hi * 16];
    float* d1 = &ctx[((size_t)b * SEQ + q0 + r1) * 256 + hi * 16];
    #pragma unroll
    for (int c4 = 0; c4 < 4; ++c4) {
      f32x4 v0, v1;
      #pragma unroll
      for (int c = 0; c < 4; ++c) { v0[c] = O0[c4*4+c] * li0; v1[c] = O1[c4*4+c] * li1; }
      *(f32x4*)&d0[c4*4] = v0;
      *(f32x4*)&d1[c4*4] = v1;
    }
  }
}

extern "C" void kernel_launch(void* const* d_in, const int* in_sizes, int n_in,
                              void* d_out, int out_size, void* d_ws, size_t ws_size,
                              hipStream_t stream) {
  (void)in_sizes; (void)n_in; (void)out_size; (void)ws_size;
  const int*   x      = (const int*)  d_in[0];
  const float* emb    = (const float*)d_in[1];
  const float* w_ih   = (const float*)d_in[2];
  const float* w_hh   = (const float*)d_in[3];
  const float* b_ih   = (const float*)d_in[4];
  const float* b_hh   = (const float*)d_in[5];
  const float* attn_w = (const float*)d_in[6];
  const float* attn_b = (const float*)d_in[7];
  const float* comb_w = (const float*)d_in[8];
  const float* comb_b = (const float*)d_in[9];
  const float* fc_w   = (const float*)d_in[10];
  const float* fc_b   = (const float*)d_in[11];
  float* out = (float*)d_out;

  // workspace layout (floats): table | all_h | keys(->combined) | ctx
  float* ws    = (float*)d_ws;
  float* table = ws;                        // 100*768      =    76800
  float* all_h = table + 76800;             // 16384*256    =  4194304
  float* keys  = all_h + 4194304;           // 16384*256    =  4194304
  float* ctx   = keys  + 4194304;           // 16384*256    =  4194304
  float* hlast = out + (size_t)NB * SEQ * NV;

  build_table<<<100, 256, 0, stream>>>(emb, w_ih, b_ih, table);
  gru_scan<<<NB, 1024, 0, stream>>>(x, w_hh, b_hh, table, all_h, hlast);
  // keys = all_h @ attn_w^T + attn_b
  gemm_bias<0><<<dim3(4, 128), 256, 0, stream>>>(all_h, 256, attn_w, attn_b, keys, 256, 256, 256);
  // ctx = softmax(causal(all_h @ keys^T)) @ all_h
  attention_kernel<<<dim3(32, 8), 256, 0, stream>>>(all_h, keys, ctx);
  // combined = tanh([all_h|ctx] @ comb_w^T + comb_b)  (into keys buffer)
  gemm_bias_cat<<<dim3(4, 128), 256, 0, stream>>>(all_h, ctx, comb_w, comb_b, keys);
  // out = combined @ fc_w^T + fc_b
  gemm_bias<0><<<dim3(2, 128), 256, 0, stream>>>(keys, 256, fc_w, fc_b, out, 100, 100, 256);
}

// Round 13
// 3151.306 us; speedup vs baseline: 1.0713x; 1.0002x over previous
//
#include <hip/hip_runtime.h>

#define SEQ  2048
#define NB   8
#define HD   256
#define G3   768
#define NV   100

typedef float f32x4 __attribute__((ext_vector_type(4)));
typedef int   i32x4 __attribute__((ext_vector_type(4)));

#define INV26 1.490116119384765625e-8f   // 2^-26

// LDS-only workgroup barrier (lgkmcnt drain, no vmcnt drain).
#define LDS_BARRIER() asm volatile("s_waitcnt lgkmcnt(0)\n\ts_barrier" ::: "memory")

__device__ __forceinline__ float sigm(float x) {
  x = fminf(fmaxf(x, -30.f), 30.f);
  return 1.f / (1.f + __expf(-x));
}
__device__ __forceinline__ float tanh_fast(float x) {
  x = fminf(fmaxf(x, -15.f), 15.f);
  float e = __expf(2.f * x);
  return (e - 1.f) / (e + 1.f);
}

// ---------------- K1: xg lookup table: table[v][g] = emb[v]·w_ih[g] + b_ih[g]
__global__ __launch_bounds__(256) void build_table(
    const float* __restrict__ emb, const float* __restrict__ w_ih,
    const float* __restrict__ b_ih, float* __restrict__ table) {
  __shared__ float eL[256];
  __shared__ float wL[256][37];
  int v = blockIdx.x, tid = threadIdx.x;
  eL[tid] = emb[v * HD + tid];
  for (int gt = 0; gt < 3; ++gt) {
    float acc = b_ih[gt * 256 + tid];
    for (int e0 = 0; e0 < HD; e0 += 32) {
      __syncthreads();
      #pragma unroll
      for (int i = 0; i < 32; ++i) {
        int idx = tid + i * 256;
        int r = idx >> 5, c = idx & 31;
        wL[r][c] = w_ih[(size_t)(gt * 256 + r) * HD + e0 + c];
      }
      __syncthreads();
      #pragma unroll
      for (int c = 0; c < 32; ++c) acc += eL[e0 + c] * wL[tid][c];
    }
    table[(size_t)v * G3 + gt * 256 + tid] = acc;
  }
}

// ---------------- K2: batch-parallel GRU scan, one WG/batch, ONE barrier/step.
// Round-12 PM: two barriers + hg LDS round-trip + chained x->table loads cost
// ~1300 cyc/step on top of the ~980 cyc MFMA floor (192 i8 MFMA/CU/step).
// Restructure: wave w owns gate-tiles rows {g*256 + w*16 + ncol} for g=0,1,2,
// so gate inputs for units j in [16w,16w+16) are wave-local: one shfl_xor(32)
// per tile combines D0 (quad0) and D8 (quad2); gates run on quad0 lanes
// in-register. hpk double-buffered (read t&1, write (t+1)&1) -> single
// end-of-step LDS barrier is WAR-safe (a wave's reads precede its barrier
// arrival). x staged in LDS once -> table gather is one un-chained L2 load
// with a full step of latency cover.
// Verified i8 fixed-point math (rounds 8-12): q_w = round(w*2^11);
// q_h = hi8*256 + lou; A row0 = hi8, row8 = lou-128;
// hg = (256*D0 + D8 + 128*sum_k q_w)*2^-26 + b_hh.
// C/D: col=lane&15, row=(lane>>4)*4+reg -> row0=(quad0,reg0), row8=(quad2,reg0).
__global__ void __launch_bounds__(1024) gru_scan(
    const int* __restrict__ x, const float* __restrict__ w_hh,
    const float* __restrict__ b_hh, const float* __restrict__ table,
    float* __restrict__ all_h, float* __restrict__ h_last) {
  __shared__ __align__(16) signed char hpk[2 * 544];  // 2 bufs x (row0 hi8 | row1 lou-128), stride 272
  __shared__ int xL[SEQ];
  const int b = blockIdx.x;
  int tid = threadIdx.x;
  int lane = tid & 63, wv = tid >> 6;       // 16 waves
  int ncol = lane & 15, quad = lane >> 4;

  for (int i = tid; i < SEQ; i += 1024) xL[i] = x[b * SEQ + i];
  for (int i = tid; i < 2 * 544; i += 1024)
    hpk[i] = ((i % 544) >= 272) ? (signed char)-128 : 0;

  // quantize weights; wave wv owns gate-tile rows g*256 + wv*16 + ncol (g = t3)
  i32x4 bw[3][4];
  float Cn[3];
  #pragma unroll
  for (int t3 = 0; t3 < 3; ++t3) {
    int row = t3 * 256 + wv * 16 + ncol;
    int sw = 0;
    #pragma unroll
    for (int c = 0; c < 4; ++c) {
      const float* p = w_hh + (size_t)row * HD + c * 64 + quad * 16;
      unsigned pw[4] = {0u, 0u, 0u, 0u};
      #pragma unroll
      for (int e = 0; e < 16; ++e) {
        int q = __float2int_rn(p[e] * 2048.f);       // w * 2^11
        q = max(-127, min(127, q));
        sw += q;
        pw[e >> 2] |= ((unsigned)(q & 255)) << ((e & 3) * 8);
      }
      bw[t3][c] = (i32x4){(int)pw[0], (int)pw[1], (int)pw[2], (int)pw[3]};
    }
    sw += __shfl_xor(sw, 16);
    sw += __shfl_xor(sw, 32);                        // full-K sum of q_w for row
    Cn[t3] = b_hh[row] + 128.f * (float)sw * INV26;
  }

  // gate identity: quad0 lanes handle hidden unit j = wv*16 + ncol
  bool gate_lane = (quad == 0);
  int j = wv * 16 + ncol;
  float hreg = 0.f, xr = 0.f, xz = 0.f, xn = 0.f;

  bool alive = (ncol & 7) == 0;                      // lanes holding nonzero A rows
  int a_base = (ncol >> 3) * 272 + quad * 16;

  __syncthreads();                                   // xL + hpk buf0 ready

  if (gate_lane) {
    int v = xL[0];
    const float* tr = table + (size_t)v * G3 + j;
    xr = tr[0]; xz = tr[256]; xn = tr[512];
  }

  for (int t = 0; t < SEQ; ++t) {
    const signed char* hc = hpk + (t & 1) * 544;
    i32x4 a[4] = {(i32x4){0,0,0,0}, (i32x4){0,0,0,0},
                  (i32x4){0,0,0,0}, (i32x4){0,0,0,0}};
    if (alive) {
      #pragma unroll
      for (int c = 0; c < 4; ++c)
        a[c] = *(const i32x4*)&hc[a_base + c * 64];
    }
    i32x4 acc[3] = {(i32x4){0,0,0,0}, (i32x4){0,0,0,0}, (i32x4){0,0,0,0}};
    #pragma unroll
    for (int c = 0; c < 4; ++c)
      #pragma unroll
      for (int t3 = 0; t3 < 3; ++t3)
        acc[t3] = __builtin_amdgcn_mfma_i32_16x16x64_i8(a[c], bw[t3][c], acc[t3], 0, 0, 0);
    float hgv[3];
    #pragma unroll
    for (int t3 = 0; t3 < 3; ++t3) {
      int ax = __shfl_xor(acc[t3][0], 32);           // D row8 from quad2
      hgv[t3] = (float)acc[t3][0] * (256.f * INV26) + (float)ax * INV26 + Cn[t3];
    }
    if (gate_lane) {
      float r = sigm(xr + hgv[0]);
      float z = sigm(xz + hgv[1]);
      float n = tanh_fast(xn + r * hgv[2]);
      float h = (1.f - z) * n + z * hreg;
      hreg = h;
      int q = min(__float2int_rn(h * 32768.f), 32767);
      int lou = q & 255;
      int hi8 = (q - lou) >> 8;
      signed char* hw = hpk + ((t + 1) & 1) * 544;
      hw[j] = (signed char)hi8;
      hw[272 + j] = (signed char)(lou - 128);
      all_h[((size_t)b * SEQ + t) * HD + j] = h;     // async store, drained at kernel end
      int tn = (t + 1 < SEQ) ? t + 1 : t;            // prefetch next step's xg (L2, un-chained)
      int v = xL[tn];
      const float* tr = table + (size_t)v * G3 + j;
      xr = tr[0]; xz = tr[256]; xn = tr[512];
    }
    LDS_BARRIER();                                   // hpk buf (t+1)&1 published
  }
  if (gate_lane) h_last[b * HD + j] = hreg;
}

// ---------------- generic f32 GEMM  C[M,N] = A[M,K]·W[N,K]^T + bias
template<int ACT>
__global__ __launch_bounds__(256) void gemm_bias(
    const float* __restrict__ A, int lda,
    const float* __restrict__ W, const float* __restrict__ bias,
    float* __restrict__ C, int ldc, int N, int K) {
  __shared__ float As[128][36];
  __shared__ float Ws[64][36];
  int tid = threadIdx.x;
  int m0 = blockIdx.y * 128, n0 = blockIdx.x * 64;
  int ml = tid & 31, g = tid >> 5;
  float acc[4][8];
  #pragma unroll
  for (int i = 0; i < 4; ++i)
    #pragma unroll
    for (int jj = 0; jj < 8; ++jj) acc[i][jj] = 0.f;
  for (int k0 = 0; k0 < K; k0 += 32) {
    __syncthreads();
    #pragma unroll
    for (int i = 0; i < 4; ++i) {
      int idx = tid + i * 256;
      int r = idx >> 3, c4 = (idx & 7) * 4;
      *(f32x4*)&As[r][c4] = *(const f32x4*)&A[(size_t)(m0 + r) * lda + k0 + c4];
    }
    #pragma unroll
    for (int i = 0; i < 2; ++i) {
      int idx = tid + i * 256;
      int r = idx >> 3, c4 = (idx & 7) * 4;
      f32x4 wv = {0.f, 0.f, 0.f, 0.f};
      if (n0 + r < N) wv = *(const f32x4*)&W[(size_t)(n0 + r) * K + k0 + c4];
      *(f32x4*)&Ws[r][c4] = wv;
    }
    __syncthreads();
    #pragma unroll
    for (int k4 = 0; k4 < 32; k4 += 4) {
      f32x4 av[4], wv8[8];
      #pragma unroll
      for (int i = 0; i < 4; ++i) av[i] = *(const f32x4*)&As[ml + i * 32][k4];
      #pragma unroll
      for (int jj = 0; jj < 8; ++jj) wv8[jj] = *(const f32x4*)&Ws[g * 8 + jj][k4];
      #pragma unroll
      for (int kk = 0; kk < 4; ++kk)
        #pragma unroll
        for (int i = 0; i < 4; ++i)
          #pragma unroll
          for (int jj = 0; jj < 8; ++jj)
            acc[i][jj] += av[i][kk] * wv8[jj][kk];
    }
  }
  #pragma unroll
  for (int i = 0; i < 4; ++i) {
    int m = m0 + ml + i * 32;
    #pragma unroll
    for (int jj = 0; jj < 8; ++jj) {
      int n = n0 + g * 8 + jj;
      if (n < N) {
        float val = acc[i][jj] + bias[n];
        if (ACT) val = tanh_fast(val);
        C[(size_t)m * ldc + n] = val;
      }
    }
  }
}

// ---------------- comb GEMM: A = [all_h | ctx] split-K (K=512), tanh epilogue
__global__ __launch_bounds__(256) void gemm_bias_cat(
    const float* __restrict__ A1, const float* __restrict__ A2,
    const float* __restrict__ W, const float* __restrict__ bias,
    float* __restrict__ C) {
  __shared__ float As[128][36];
  __shared__ float Ws[64][36];
  const int K = 512;
  int tid = threadIdx.x;
  int m0 = blockIdx.y * 128, n0 = blockIdx.x * 64;
  int ml = tid & 31, g = tid >> 5;
  float acc[4][8];
  #pragma unroll
  for (int i = 0; i < 4; ++i)
    #pragma unroll
    for (int jj = 0; jj < 8; ++jj) acc[i][jj] = 0.f;
  for (int k0 = 0; k0 < K; k0 += 32) {
    const float* src = (k0 < 256) ? A1 : A2;
    int kb = (k0 < 256) ? k0 : k0 - 256;
    __syncthreads();
    #pragma unroll
    for (int i = 0; i < 4; ++i) {
      int idx = tid + i * 256;
      int r = idx >> 3, c4 = (idx & 7) * 4;
      *(f32x4*)&As[r][c4] = *(const f32x4*)&src[(size_t)(m0 + r) * 256 + kb + c4];
    }
    #pragma unroll
    for (int i = 0; i < 2; ++i) {
      int idx = tid + i * 256;
      int r = idx >> 3, c4 = (idx & 7) * 4;
      *(f32x4*)&Ws[r][c4] = *(const f32x4*)&W[(size_t)(n0 + r) * K + k0 + c4];
    }
    __syncthreads();
    #pragma unroll
    for (int k4 = 0; k4 < 32; k4 += 4) {
      f32x4 av[4], wv8[8];
      #pragma unroll
      for (int i = 0; i < 4; ++i) av[i] = *(const f32x4*)&As[ml + i * 32][k4];
      #pragma unroll
      for (int jj = 0; jj < 8; ++jj) wv8[jj] = *(const f32x4*)&Ws[g * 8 + jj][k4];
      #pragma unroll
      for (int kk = 0; kk < 4; ++kk)
        #pragma unroll
        for (int i = 0; i < 4; ++i)
          #pragma unroll
          for (int jj = 0; jj < 8; ++jj)
            acc[i][jj] += av[i][kk] * wv8[jj][kk];
    }
  }
  #pragma unroll
  for (int i = 0; i < 4; ++i) {
    int m = m0 + ml + i * 32;
    #pragma unroll
    for (int jj = 0; jj < 8; ++jj) {
      int n = n0 + g * 8 + jj;
      C[(size_t)m * 256 + n] = tanh_fast(acc[i][jj] + bias[n]);
    }
  }
}

// ---------------- K4: causal flash attention, q-tile 32 / k-tile 16, all f32.
// Block (jb, b) handles q-tiles jb and 63-jb (balances the causal triangle).
// Qs/Ks XOR-swizzled -> conflict-free score loop.
__global__ __launch_bounds__(256) void attention_kernel(
    const float* __restrict__ all_h, const float* __restrict__ keys,
    float* __restrict__ ctx) {
  __shared__ float Qs[32 * 256];
  __shared__ float Ks[16 * 256];
  __shared__ float Hs[16 * 256];
  __shared__ float Sl[32][17];
  __shared__ float mL[32], lL[32], aL[32];
  int b = blockIdx.y, jb = blockIdx.x, tid = threadIdx.x;
  const float* hb = all_h + (size_t)b * SEQ * HD;
  const float* kb = keys  + (size_t)b * SEQ * HD;
  int qg = tid & 15, hi = tid >> 4;
  int r0 = qg * 2, r1 = r0 + 1;
  int sq = qg & 7;                          // Q swizzle bits for rows r0,r1
  for (int phase = 0; phase < 2; ++phase) {
    int qt = phase ? (63 - jb) : jb;
    int q0 = qt * 32;
    __syncthreads();
    #pragma unroll
    for (int i = 0; i < 8; ++i) {           // stage Q 32x256 (swizzled)
      int idx = tid + i * 256;
      int r = idx >> 6, cg = idx & 63;
      *(f32x4*)&Qs[r * 256 + ((cg ^ ((r >> 1) & 7)) << 2)] =
          *(const f32x4*)&hb[(size_t)(q0 + r) * HD + cg * 4];
    }
    if (tid < 32) { mL[tid] = -3e38f; lL[tid] = 0.f; }
    float O0[16], O1[16];
    #pragma unroll
    for (int c = 0; c < 16; ++c) { O0[c] = 0.f; O1[c] = 0.f; }
    int nkt = 2 * (qt + 1);
    for (int kt = 0; kt < nkt; ++kt) {
      int k0 = kt * 16;
      __syncthreads();
      #pragma unroll
      for (int i = 0; i < 4; ++i) {         // stage K (swizzled) + V, 16x256 each
        int idx = tid + i * 256;
        int r = idx >> 6, cg = idx & 63;
        *(f32x4*)&Ks[r * 256 + ((cg ^ (r & 7)) << 2)] =
            *(const f32x4*)&kb[(size_t)(k0 + r) * HD + cg * 4];
        *(f32x4*)&Hs[r * 256 + cg * 4] = *(const f32x4*)&hb[(size_t)(k0 + r) * HD + cg * 4];
      }
      __syncthreads();
      int kc = hi;
      int sk = kc & 7;
      float sc0 = 0.f, sc1 = 0.f;
      #pragma unroll 8
      for (int c = 0; c < 64; ++c) {
        f32x4 kv  = *(const f32x4*)&Ks[kc * 256 + ((c ^ sk) << 2)];
        f32x4 q0v = *(const f32x4*)&Qs[r0 * 256 + ((c ^ sq) << 2)];
        f32x4 q1v = *(const f32x4*)&Qs[r1 * 256 + ((c ^ sq) << 2)];
        sc0 += q0v[0]*kv[0] + q0v[1]*kv[1] + q0v[2]*kv[2] + q0v[3]*kv[3];
        sc1 += q1v[0]*kv[0] + q1v[1]*kv[1] + q1v[2]*kv[2] + q1v[3]*kv[3];
      }
      int kabs = k0 + kc;
      Sl[r0][kc] = (kabs <= q0 + r0) ? sc0 : -3e38f;
      Sl[r1][kc] = (kabs <= q0 + r1) ? sc1 : -3e38f;
      __syncthreads();
      if (tid < 32) {                       // online softmax per q-row
        float mo = mL[tid], mn = mo;
        #pragma unroll
        for (int c = 0; c < 16; ++c) mn = fmaxf(mn, Sl[tid][c]);
        float al = __expf(mo - mn);
        float sm = 0.f;
        #pragma unroll
        for (int c = 0; c < 16; ++c) {
          float p = __expf(Sl[tid][c] - mn);
          Sl[tid][c] = p; sm += p;
        }
        lL[tid] = lL[tid] * al + sm;
        mL[tid] = mn;
        aL[tid] = al;
      }
      __syncthreads();
      float a0 = aL[r0], a1 = aL[r1];
      #pragma unroll
      for (int c = 0; c < 16; ++c) { O0[c] *= a0; O1[c] *= a1; }
      #pragma unroll
      for (int k = 0; k < 16; ++k) {
        float p0 = Sl[r0][k], p1 = Sl[r1][k];
        #pragma unroll
        for (int c4 = 0; c4 < 4; ++c4) {
          f32x4 hh = *(const f32x4*)&Hs[k * 256 + hi * 16 + c4 * 4];
          O0[c4*4+0] += p0 * hh[0]; O0[c4*4+1] += p0 * hh[1];
          O0[c4*4+2] += p0 * hh[2]; O0[c4*4+3] += p0 * hh[3];
          O1[c4*4+0] += p1 * hh[0]; O1[c4*4+1] += p1 * hh[1];
          O1[c4*4+2] += p1 * hh[2]; O1[c4*4+3] += p1 * hh[3];
        }
      }
    }
    float li0 = 1.f / lL[r0], li1 = 1.f / lL[r1];
    float* d0 = &ctx[((size_t)b * SEQ + q0 + r0) * 256 + hi * 16];
    float* d1 = &ctx[((size_t)b * SEQ + q0 + r1) * 256 + hi * 16];
    #pragma unroll
    for (int c4 = 0; c4 < 4; ++c4) {
      f32x4 v0, v1;
      #pragma unroll
      for (int c = 0; c < 4; ++c) { v0[c] = O0[c4*4+c] * li0; v1[c] = O1[c4*4+c] * li1; }
      *(f32x4*)&d0[c4*4] = v0;
      *(f32x4*)&d1[c4*4] = v1;
    }
  }
}

extern "C" void kernel_launch(void* const* d_in, const int* in_sizes, int n_in,
                              void* d_out, int out_size, void* d_ws, size_t ws_size,
                              hipStream_t stream) {
  (void)in_sizes; (void)n_in; (void)out_size; (void)ws_size;
  const int*   x      = (const int*)  d_in[0];
  const float* emb    = (const float*)d_in[1];
  const float* w_ih   = (const float*)d_in[2];
  const float* w_hh   = (const float*)d_in[3];
  const float* b_ih   = (const float*)d_in[4];
  const float* b_hh   = (const float*)d_in[5];
  const float* attn_w = (const float*)d_in[6];
  const float* attn_b = (const float*)d_in[7];
  const float* comb_w = (const float*)d_in[8];
  const float* comb_b = (const float*)d_in[9];
  const float* fc_w   = (const float*)d_in[10];
  const float* fc_b   = (const float*)d_in[11];
  float* out = (float*)d_out;

  // workspace layout (floats): table | all_h | keys(->combined) | ctx
  float* ws    = (float*)d_ws;
  float* table = ws;                        // 100*768      =    76800
  float* all_h = table + 76800;             // 16384*256    =  4194304
  float* keys  = all_h + 4194304;           // 16384*256    =  4194304
  float* ctx   = keys  + 4194304;           // 16384*256    =  4194304
  float* hlast = out + (size_t)NB * SEQ * NV;

  build_table<<<100, 256, 0, stream>>>(emb, w_ih, b_ih, table);
  gru_scan<<<NB, 1024, 0, stream>>>(x, w_hh, b_hh, table, all_h, hlast);
  // keys = all_h @ attn_w^T + attn_b
  gemm_bias<0><<<dim3(4, 128), 256, 0, stream>>>(all_h, 256, attn_w, attn_b, keys, 256, 256, 256);
  // ctx = softmax(causal(all_h @ keys^T)) @ all_h
  attention_kernel<<<dim3(32, 8), 256, 0, stream>>>(all_h, keys, ctx);
  // combined = tanh([all_h|ctx] @ comb_w^T + comb_b)  (into keys buffer)
  gemm_bias_cat<<<dim3(4, 128), 256, 0, stream>>>(all_h, ctx, comb_w, comb_b, keys);
  // out = combined @ fc_w^T + fc_b
  gemm_bias<0><<<dim3(2, 128), 256, 0, stream>>>(keys, 256, fc_w, fc_b, out, 100, 100, 256);
}